// Round 7
// baseline (89.962 us; speedup 1.0000x reference)
//
#include <hip/hip_runtime.h>
#include <math.h>

#define S 1024
#define D 64
#define BND 0.99999994f
#define FINF 3.4e38f
#define C4(v,c) ((&(v).x)[c])

__device__ __forceinline__ float waveSum(float v){
  #pragma unroll
  for(int o=32;o>0;o>>=1) v += __shfl_xor(v,o,64);
  return v;
}
__device__ __forceinline__ float4 mk4(const float* a){
  float4 r; r.x=a[0]; r.y=a[1]; r.z=a[2]; r.w=a[3]; return r;
}
// 512-thread packed reductions: 4 queries per call, one barrier pair.
__device__ __forceinline__ float4 blockSum512_v4(float4 v, float4* red4){
  #pragma unroll
  for(int o=32;o>0;o>>=1){
    v.x+=__shfl_xor(v.x,o,64); v.y+=__shfl_xor(v.y,o,64);
    v.z+=__shfl_xor(v.z,o,64); v.w+=__shfl_xor(v.w,o,64);
  }
  const int wid=threadIdx.x>>6;
  __syncthreads();
  if((threadIdx.x&63)==0) red4[wid]=v;
  __syncthreads();
  float4 s={0.f,0.f,0.f,0.f};
  #pragma unroll
  for(int k=0;k<8;k++){ float4 r=red4[k]; s.x+=r.x; s.y+=r.y; s.z+=r.z; s.w+=r.w; }
  return s;
}
__device__ __forceinline__ float4 blockMin512_v4(float4 v, float4* red4){
  #pragma unroll
  for(int o=32;o>0;o>>=1){
    v.x=fminf(v.x,__shfl_xor(v.x,o,64)); v.y=fminf(v.y,__shfl_xor(v.y,o,64));
    v.z=fminf(v.z,__shfl_xor(v.z,o,64)); v.w=fminf(v.w,__shfl_xor(v.w,o,64));
  }
  const int wid=threadIdx.x>>6;
  __syncthreads();
  if((threadIdx.x&63)==0) red4[wid]=v;
  __syncthreads();
  float4 s=red4[0];
  #pragma unroll
  for(int k=1;k<8;k++){ float4 r=red4[k]; s.x=fminf(s.x,r.x); s.y=fminf(s.y,r.y); s.z=fminf(s.z,r.z); s.w=fminf(s.w,r.w); }
  return s;
}

// K1: q/k/v projections, expmap0(q), expmap0(k), norms, v_r init, + transposed k_hypT
__global__ __launch_bounds__(64) void k_proj(
  const float* __restrict__ qin, const float* __restrict__ kin, const float* __restrict__ vin,
  const float* __restrict__ Wq, const float* __restrict__ bq,
  const float* __restrict__ Wk, const float* __restrict__ bk,
  const float* __restrict__ Wv, const float* __restrict__ bv,
  const float* __restrict__ vrand,
  float* __restrict__ q_hyp, float* __restrict__ k_hyp, float* __restrict__ kT,
  float* __restrict__ vproj, float* __restrict__ kproj,
  float* __restrict__ q2, float* __restrict__ k2, float* __restrict__ v_r)
{
  const int i = blockIdx.x, d = threadIdx.x;
  __shared__ __align__(16) float lq[D], lk[D], lv[D];
  lq[d]=qin[i*D+d]; lk[d]=kin[i*D+d]; lv[d]=vin[i*D+d];
  __syncthreads();
  float aq=bq[d], ak=bk[d], av=bv[d];
  const float4* wq4=(const float4*)(Wq + d*D);
  const float4* wk4=(const float4*)(Wk + d*D);
  const float4* wv4=(const float4*)(Wv + d*D);
  #pragma unroll
  for(int e=0;e<16;e++){
    float4 a=wq4[e], b=wk4[e], c=wv4[e];
    aq += lq[4*e]*a.x + lq[4*e+1]*a.y + lq[4*e+2]*a.z + lq[4*e+3]*a.w;
    ak += lk[4*e]*b.x + lk[4*e+1]*b.y + lk[4*e+2]*b.z + lk[4*e+3]*b.w;
    av += lv[4*e]*c.x + lv[4*e+1]*c.y + lv[4*e+2]*c.z + lv[4*e+3]*c.w;
  }
  float nq = sqrtf(waveSum(aq*aq)+1e-15f);
  float qh = tanhf(nq)*aq/nq;
  q_hyp[i*D+d]=qh;
  float q2v = waveSum(qh*qh);
  if(d==0) q2[i]=q2v;
  float nk = sqrtf(waveSum(ak*ak)+1e-15f);
  float kh = tanhf(nk)*ak/nk;
  k_hyp[i*D+d]=kh;
  kT[(size_t)d*S + i]=kh;
  float k2v = waveSum(kh*kh);
  if(d==0) k2[i]=k2v;
  vproj[i*D+d]=av;
  kproj[i*D+d]=ak;
  float vr = vrand[i*D+d];
  float nn = sqrtf(waveSum(vr*vr));
  v_r[i*D+d] = vr/fmaxf(nn,1e-12f);
}

// K2 (fully fused): 4 queries/block, 512 threads, grid 256 (1 block/CU).
//  P1: dist->min->w->wsum->entropy   (1 kT sweep shared by 4 queries)
//  P2: h, centroid+expmap0           (vproj sweep, kproj sweep)
//  PA: a,b coefs, var, tension       (1 kT sweep)
//  PB: 3 power iterations            (kT sweep + k_hyp sweep each)
//  PC: bifurcation epilogue + out GEMV
__global__ __launch_bounds__(512,2) void k_fused(
  const float* __restrict__ q_hyp_g, const float* __restrict__ k_hyp,
  const float* __restrict__ kT,
  const float* __restrict__ q2a, const float* __restrict__ k2a,
  const float* __restrict__ vproj, const float* __restrict__ kproj,
  const float* __restrict__ v_r, const float* __restrict__ tau_p,
  const float* __restrict__ gu, const float* __restrict__ gamma_p,
  const float* __restrict__ ts_p, const float* __restrict__ Wo,
  const float* __restrict__ bo, float* __restrict__ out)
{
  const int i0=blockIdx.x*4, tid=threadIdx.x;
  __shared__ __align__(16) float qv[4][D];
  __shared__ __align__(16) float cv[4][D];
  __shared__ __align__(16) float vv[4][D];
  __shared__ __align__(16) float hl[4][D];
  __shared__ __align__(16) float fus[4][D];
  __shared__ __align__(16) float wl[4][S];      // w in P1/P2/PA; aliased as prow in PB
  __shared__ __align__(16) float aal[4][S];
  __shared__ __align__(16) float bbl[4][S];
  __shared__ __align__(16) float4 sA[2048];     // 32KB: pjoin [2][4][256]f4  /  part floats [128][64]
  __shared__ __align__(16) float4 red4[8];
  __shared__ float scal[4][6];  // 0:var 1:tension 2:cdot 3:effm 4:c2
  float* const pA=(float*)sA;

  if(tid<256){ qv[tid>>6][tid&63]=q_hyp_g[i0*D+tid]; vv[tid>>6][tid&63]=v_r[i0*D+tid]; }
  __syncthreads();

  const int jf=tid&255, dh=tid>>8;     // dh constant within a wave
  const int qq0=dh, qq1=dh+2;
  const int dq=tid&15, g=tid>>4;
  const float4* kT4=(const float4*)kT;
  const float tau=tau_p[0];

  // ================= P1: weights =================
  {
    float4 p0={0,0,0,0},p1={0,0,0,0},p2={0,0,0,0},p3={0,0,0,0};
    #pragma unroll 8
    for(int dd=0; dd<32; ++dd){
      const int d=(dh<<5)+dd;
      const float4 y=kT4[d*256+jf];
      const float c0=qv[0][d], c1=qv[1][d], c2q=qv[2][d], c3=qv[3][d];
      p0.x+=c0*y.x; p0.y+=c0*y.y; p0.z+=c0*y.z; p0.w+=c0*y.w;
      p1.x+=c1*y.x; p1.y+=c1*y.y; p1.z+=c1*y.z; p1.w+=c1*y.w;
      p2.x+=c2q*y.x; p2.y+=c2q*y.y; p2.z+=c2q*y.z; p2.w+=c2q*y.w;
      p3.x+=c3*y.x; p3.y+=c3*y.y; p3.z+=c3*y.z; p3.w+=c3*y.w;
    }
    sA[(dh*4+0)*256+jf]=p0; sA[(dh*4+1)*256+jf]=p1;
    sA[(dh*4+2)*256+jf]=p2; sA[(dh*4+3)*256+jf]=p3;
  }
  __syncthreads();
  float4 inv4;
  {
    const float4 y2v=((const float4*)k2a)[jf];
    const float x2q[2]={q2a[i0+qq0], q2a[i0+qq1]};
    float dist[2][4];
    float4 mn4={FINF,FINF,FINF,FINF};
    #pragma unroll
    for(int it=0; it<2; ++it){
      const int qq = it? qq1:qq0;
      const float4 da=sA[(0*4+qq)*256+jf], db=sA[(1*4+qq)*256+jf];
      const float x2=x2q[it], B=1.f-x2;
      #pragma unroll
      for(int c=0;c<4;c++){
        const float y2=C4(y2v,c);
        const float dot=C4(da,c)+C4(db,c);
        const float A=1.f-2.f*dot+y2;
        const float den=fmaxf(1.f-2.f*dot+x2*y2,1e-15f);
        const float num2=fmaxf(A*A*x2 + B*B*y2 - 2.f*A*B*dot, 0.f);
        const float nn=sqrtf(num2/(den*den)+1e-15f);
        dist[it][c]=2.f*atanhf(fminf(nn,BND));
        C4(mn4,qq)=fminf(C4(mn4,qq),dist[it][c]);
      }
    }
    mn4=blockMin512_v4(mn4,red4);
    float w[2][4];
    float4 s4={0,0,0,0};
    #pragma unroll
    for(int it=0; it<2; ++it){
      const int qq = it? qq1:qq0;
      #pragma unroll
      for(int c=0;c<4;c++){ w[it][c]=expf(C4(mn4,qq)-dist[it][c]); C4(s4,qq)+=w[it][c]; }
      ((float4*)&wl[qq][0])[jf]=mk4(w[it]);
    }
    s4=blockSum512_v4(s4,red4);
    inv4.x=1.f/(s4.x+1e-8f); inv4.y=1.f/(s4.y+1e-8f);
    inv4.z=1.f/(s4.z+1e-8f); inv4.w=1.f/(s4.w+1e-8f);
    float4 e4={0,0,0,0};
    #pragma unroll
    for(int it=0; it<2; ++it){
      const int qq = it? qq1:qq0;
      #pragma unroll
      for(int c=0;c<4;c++){
        const float p=w[it][c]*C4(inv4,qq);
        C4(e4,qq) -= p*logf(p+1e-8f);
      }
    }
    e4=blockSum512_v4(e4,red4);
    if(tid<4) scal[tid][3]=expf(C4(e4,tid));
  }

  // ================= P2: h + centroid =================
  {
    float4 a0={0,0,0,0},a1={0,0,0,0},a2={0,0,0,0},a3={0,0,0,0};
    #pragma unroll 4
    for(int jj=0;jj<32;jj++){
      const int j=jj*32+g;
      const float4 y=((const float4*)(vproj + j*D))[dq];
      const float u0=wl[0][j],u1=wl[1][j],u2=wl[2][j],u3=wl[3][j];
      a0.x+=u0*y.x; a0.y+=u0*y.y; a0.z+=u0*y.z; a0.w+=u0*y.w;
      a1.x+=u1*y.x; a1.y+=u1*y.y; a1.z+=u1*y.z; a1.w+=u1*y.w;
      a2.x+=u2*y.x; a2.y+=u2*y.y; a2.z+=u2*y.z; a2.w+=u2*y.w;
      a3.x+=u3*y.x; a3.y+=u3*y.y; a3.z+=u3*y.z; a3.w+=u3*y.w;
    }
    __syncthreads();   // sA pjoin reads done (P1 combine) before overwrite
    *(float4*)&pA[(g*4+0)*64+dq*4]=a0; *(float4*)&pA[(g*4+1)*64+dq*4]=a1;
    *(float4*)&pA[(g*4+2)*64+dq*4]=a2; *(float4*)&pA[(g*4+3)*64+dq*4]=a3;
    __syncthreads();
    if(tid<256){
      const int q=tid>>6, d=tid&63;
      float hs=0.f;
      #pragma unroll 8
      for(int gg=0;gg<32;gg++) hs+=pA[(gg*4+q)*64+d];
      hl[q][d]=hs*C4(inv4,q);
    }
    __syncthreads();
    float4 b0={0,0,0,0},b1={0,0,0,0},b2={0,0,0,0},b3={0,0,0,0};
    #pragma unroll 4
    for(int jj=0;jj<32;jj++){
      const int j=jj*32+g;
      const float4 y=((const float4*)(kproj + j*D))[dq];
      const float u0=wl[0][j],u1=wl[1][j],u2=wl[2][j],u3=wl[3][j];
      b0.x+=u0*y.x; b0.y+=u0*y.y; b0.z+=u0*y.z; b0.w+=u0*y.w;
      b1.x+=u1*y.x; b1.y+=u1*y.y; b1.z+=u1*y.z; b1.w+=u1*y.w;
      b2.x+=u2*y.x; b2.y+=u2*y.y; b2.z+=u2*y.z; b2.w+=u2*y.w;
      b3.x+=u3*y.x; b3.y+=u3*y.y; b3.z+=u3*y.z; b3.w+=u3*y.w;
    }
    *(float4*)&pA[(g*4+0)*64+dq*4]=b0; *(float4*)&pA[(g*4+1)*64+dq*4]=b1;
    *(float4*)&pA[(g*4+2)*64+dq*4]=b2; *(float4*)&pA[(g*4+3)*64+dq*4]=b3;
    __syncthreads();
    if(tid<256){
      const int q=tid>>6, d=tid&63;
      float cs=0.f;
      #pragma unroll 8
      for(int gg=0;gg<32;gg++) cs+=pA[(gg*4+q)*64+d];
      const float ca=cs*C4(inv4,q);
      const float n=sqrtf(waveSum(ca*ca)+1e-15f);
      const float ch=tanhf(n)*ca/n;
      cv[q][d]=ch;
      const float c2v=waveSum(ch*ch);
      if(d==0) scal[q][4]=c2v;
    }
  }
  __syncthreads();

  // ================= PA: coefficients =================
  {
    float4 p0={0,0,0,0},p1={0,0,0,0},p2={0,0,0,0},p3={0,0,0,0};
    #pragma unroll 8
    for(int dd=0; dd<32; ++dd){
      const int d=(dh<<5)+dd;
      const float4 y=kT4[d*256+jf];
      const float c0=cv[0][d], c1=cv[1][d], c2q=cv[2][d], c3=cv[3][d];
      p0.x+=c0*y.x; p0.y+=c0*y.y; p0.z+=c0*y.z; p0.w+=c0*y.w;
      p1.x+=c1*y.x; p1.y+=c1*y.y; p1.z+=c1*y.z; p1.w+=c1*y.w;
      p2.x+=c2q*y.x; p2.y+=c2q*y.y; p2.z+=c2q*y.z; p2.w+=c2q*y.w;
      p3.x+=c3*y.x; p3.y+=c3*y.y; p3.z+=c3*y.z; p3.w+=c3*y.w;
    }
    sA[(dh*4+0)*256+jf]=p0; sA[(dh*4+1)*256+jf]=p1;
    sA[(dh*4+2)*256+jf]=p2; sA[(dh*4+3)*256+jf]=p3;
  }
  __syncthreads();
  {
    const float4 y2v=((const float4*)k2a)[jf];
    float4 var4={0,0,0,0};
    #pragma unroll
    for(int it=0; it<2; ++it){
      const int qq = it? qq1:qq0;
      const float4 da=sA[(0*4+qq)*256+jf], db=sA[(1*4+qq)*256+jf];
      const float4 wv=((float4*)&wl[qq][0])[jf];
      const float x2=scal[qq][4];
      const float Bc=1.f-x2, mB=fmaxf(Bc,1e-15f), inv=C4(inv4,qq);
      float ac[4], bc[4];
      #pragma unroll
      for(int c=0;c<4;c++){
        const float y2=C4(y2v,c);
        const float dot=C4(da,c)+C4(db,c);
        const float A=1.f-2.f*dot+y2;
        const float den=fmaxf(1.f-2.f*dot+x2*y2,1e-15f);
        const float num2=fmaxf(A*A*x2+Bc*Bc*y2-2.f*A*Bc*dot,0.f);
        const float nn=sqrtf(num2/(den*den)+1e-15f);
        const float art=atanhf(fminf(nn,BND));
        const float w=C4(wv,c);
        C4(var4,qq) += w*inv*4.f*art*art;
        const float coef=sqrtf(w+1e-8f)*mB*art/(nn*den);
        ac[c]=-coef*A; bc[c]=coef*Bc;
      }
      ((float4*)&aal[qq][0])[jf]=mk4(ac);
      ((float4*)&bbl[qq][0])[jf]=mk4(bc);
    }
    var4=blockSum512_v4(var4,red4);
    if(tid<4){ scal[tid][0]=C4(var4,tid); scal[tid][1]=C4(var4,tid) - tau*scal[tid][3]; }
  }
  // wl is dead from here; reuse as prow[4][S]
  float* const prow0=&wl[0][0];

  // ================= PB: 3 power iterations =================
  for(int it3=0; it3<3; ++it3){
    __syncthreads();  // sA free, vv/scal/aal/bbl published
    if(tid<256){
      const int q=tid>>6, d=tid&63;
      const float cd=waveSum(cv[q][d]*vv[q][d]);
      if(d==0) scal[q][2]=cd;
    }
    __syncthreads();
    const float cd0=scal[0][2], cd1=scal[1][2], cd2=scal[2][2], cd3=scal[3][2];
    {
      float4 p0={0,0,0,0},p1={0,0,0,0},p2={0,0,0,0},p3={0,0,0,0};
      #pragma unroll 8
      for(int dd=0; dd<32; ++dd){
        const int d=(dh<<5)+dd;
        const float4 y=kT4[d*256+jf];
        const float c0=vv[0][d], c1=vv[1][d], c2q=vv[2][d], c3=vv[3][d];
        p0.x+=c0*y.x; p0.y+=c0*y.y; p0.z+=c0*y.z; p0.w+=c0*y.w;
        p1.x+=c1*y.x; p1.y+=c1*y.y; p1.z+=c1*y.z; p1.w+=c1*y.w;
        p2.x+=c2q*y.x; p2.y+=c2q*y.y; p2.z+=c2q*y.z; p2.w+=c2q*y.w;
        p3.x+=c3*y.x; p3.y+=c3*y.y; p3.z+=c3*y.z; p3.w+=c3*y.w;
      }
      sA[(dh*4+0)*256+jf]=p0; sA[(dh*4+1)*256+jf]=p1;
      sA[(dh*4+2)*256+jf]=p2; sA[(dh*4+3)*256+jf]=p3;
    }
    __syncthreads();
    float4 sal4={0,0,0,0};
    {
      const float cdq[2]={ dh? cd1:cd0, dh? cd3:cd2 };
      #pragma unroll
      for(int it=0; it<2; ++it){
        const int qq = it? qq1:qq0;
        const float4 da=sA[(0*4+qq)*256+jf], db=sA[(1*4+qq)*256+jf];
        const float4 av=((float4*)&aal[qq][0])[jf];
        const float4 bv=((float4*)&bbl[qq][0])[jf];
        float pr[4];
        #pragma unroll
        for(int c=0;c<4;c++){
          const float t=C4(da,c)+C4(db,c);
          const float p=C4(av,c)*cdq[it] + C4(bv,c)*t;
          pr[c]=p*C4(bv,c);
          C4(sal4,qq) += p*C4(av,c);
        }
        ((float4*)&prow0[qq*S])[jf]=mk4(pr);
      }
    }
    sal4=blockSum512_v4(sal4,red4);   // also publishes prow
    {
      float4 a0={0,0,0,0},a1={0,0,0,0},a2={0,0,0,0},a3={0,0,0,0};
      #pragma unroll 4
      for(int jj=0;jj<32;jj++){
        const int j=jj*32+g;
        const float4 y=((const float4*)(k_hyp + j*D))[dq];
        const float u0=prow0[0*S+j],u1=prow0[1*S+j],u2=prow0[2*S+j],u3=prow0[3*S+j];
        a0.x+=u0*y.x; a0.y+=u0*y.y; a0.z+=u0*y.z; a0.w+=u0*y.w;
        a1.x+=u1*y.x; a1.y+=u1*y.y; a1.z+=u1*y.z; a1.w+=u1*y.w;
        a2.x+=u2*y.x; a2.y+=u2*y.y; a2.z+=u2*y.z; a2.w+=u2*y.w;
        a3.x+=u3*y.x; a3.y+=u3*y.y; a3.z+=u3*y.z; a3.w+=u3*y.w;
      }
      *(float4*)&pA[(g*4+0)*64+dq*4]=a0; *(float4*)&pA[(g*4+1)*64+dq*4]=a1;
      *(float4*)&pA[(g*4+2)*64+dq*4]=a2; *(float4*)&pA[(g*4+3)*64+dq*4]=a3;
    }
    __syncthreads();
    if(tid<256){
      const int q=tid>>6, d=tid&63;
      float od=C4(sal4,q)*cv[q][d];
      #pragma unroll 8
      for(int gg=0;gg<32;gg++) od += pA[(gg*4+q)*64+d];
      const float nn=sqrtf(waveSum(od*od));
      vv[q][d]=od/fmaxf(nn,1e-12f);
    }
  }
  __syncthreads();

  // ================= PC: epilogue + out GEMV =================
  if(tid<256){
    const int q=tid>>6, d=tid&63;
    const int i=i0+q;
    const float x2q_c=scal[q][4];
    const float vd=vv[q][d];
    const float vars=scal[q][0], tns=scal[q][1];
    const float hd=hl[q][d];
    const float qd=qv[q][d];
    const float q2=q2a[i];
    const float wpg=vd/fmaxf(1.f-x2q_c,1e-15f);
    const float nq=sqrtf(q2+1e-15f);
    const float qt=atanhf(fminf(nq,BND))*qd/nq;
    const float ncn=sqrtf(x2q_c+1e-15f);
    const float ct=atanhf(fminf(ncn,BND))*cv[q][d]/ncn;
    const float df=qt-ct;
    const float nd=sqrtf(waveSum(df*df));
    const float fb=df/fmaxf(nd,1e-8f);
    const float wp=(vars>1e-5f)?wpg:fb;
    const float hn=sqrtf(waveSum(hd*hd)+1e-15f);
    const float hc=asinhf(hn)*hd/(hn+1e-8f);
    const float x=waveSum(hc*wp);
    const float hmag=sqrtf(waveSum(hc*hc)+1e-15f);
    const float amp=(tns>0.f)? hmag*tanhf(tns) : 0.f;
    const float u0=gu[i*2], u1=gu[i*2+1];
    const float eg=(u0>=u1)?1.f:-1.f;
    const float dc=tanhf(eg*amp - x);
    const float hp=hc+dc*wp;
    const float hpn=sqrtf(waveSum(hp*hp)+1e-15f)+1e-8f;
    const float hpb=hp*(tanhf(hpn*ts_p[0])/hpn);
    const float n2=sqrtf(waveSum(hpb*hpb)+1e-15f);
    const float hyp=tanhf(n2)*hpb/n2;
    const float n3=sqrtf(waveSum(hyp*hyp)+1e-15f);
    const float bif=atanhf(fminf(n3,BND))*hyp/n3;
    const float gate=1.f/(1.f+expf(-gamma_p[0]));
    fus[q][d]=(1.f-gate)*hd + gate*bif;
  }
  __syncthreads();
  if(tid<256){
    const int q=tid>>6, d=tid&63;
    float acc=bo[d];
    const float4* wo4=(const float4*)(Wo + d*D);
    #pragma unroll
    for(int e=0;e<16;e++){
      float4 wv=wo4[e];
      acc += fus[q][4*e]*wv.x + fus[q][4*e+1]*wv.y + fus[q][4*e+2]*wv.z + fus[q][4*e+3]*wv.w;
    }
    out[(i0+q)*D+d]=acc;
  }
}

extern "C" void kernel_launch(void* const* d_in, const int* in_sizes, int n_in,
                              void* d_out, int out_size, void* d_ws, size_t ws_size,
                              hipStream_t stream)
{
  const float* qin=(const float*)d_in[0];
  const float* kin=(const float*)d_in[1];
  const float* vin=(const float*)d_in[2];
  const float* Wq=(const float*)d_in[3];
  const float* bq=(const float*)d_in[4];
  const float* Wk=(const float*)d_in[5];
  const float* bk=(const float*)d_in[6];
  const float* Wv=(const float*)d_in[7];
  const float* bv=(const float*)d_in[8];
  const float* Wo=(const float*)d_in[9];
  const float* bo=(const float*)d_in[10];
  const float* tau=(const float*)d_in[11];
  const float* gamma=(const float*)d_in[12];
  const float* tscale=(const float*)d_in[13];
  const float* gu=(const float*)d_in[14];
  const float* vrand=(const float*)d_in[15];
  float* out=(float*)d_out;

  float* p=(float*)d_ws;
  float* q_hyp=p; p+=S*D;
  float* k_hyp=p; p+=S*D;
  float* kT=p;    p+=S*D;
  float* vproj=p; p+=S*D;
  float* kproj=p; p+=S*D;
  float* v_r=p;   p+=S*D;
  float* q2=p;   p+=S;
  float* k2=p;   p+=S;

  k_proj<<<S,64,0,stream>>>(qin,kin,vin,Wq,bq,Wk,bk,Wv,bv,vrand,
                            q_hyp,k_hyp,kT,vproj,kproj,q2,k2,v_r);
  k_fused<<<S/4,512,0,stream>>>(q_hyp,k_hyp,kT,q2,k2,vproj,kproj,v_r,
                                tau,gu,gamma,tscale,Wo,bo,out);
}

// Round 8
// 86.814 us; speedup vs baseline: 1.0363x; 1.0363x over previous
//
#include <hip/hip_runtime.h>
#include <math.h>

#define S 1024
#define D 64
#define BND 0.99999994f
#define FINF 3.4e38f
#define C4(v,c) ((&(v).x)[c])
#define FMA4(acc,s,v) { (acc).x+=(s)*(v).x; (acc).y+=(s)*(v).y; (acc).z+=(s)*(v).z; (acc).w+=(s)*(v).w; }

__device__ __forceinline__ float waveSum(float v){
  #pragma unroll
  for(int o=32;o>0;o>>=1) v += __shfl_xor(v,o,64);
  return v;
}
__device__ __forceinline__ float4 mk4(const float* a){
  float4 r; r.x=a[0]; r.y=a[1]; r.z=a[2]; r.w=a[3]; return r;
}
// 512-thread packed reductions: 4 queries per call, one barrier pair.
__device__ __forceinline__ float4 blockSum512_v4(float4 v, float4* red4){
  #pragma unroll
  for(int o=32;o>0;o>>=1){
    v.x+=__shfl_xor(v.x,o,64); v.y+=__shfl_xor(v.y,o,64);
    v.z+=__shfl_xor(v.z,o,64); v.w+=__shfl_xor(v.w,o,64);
  }
  const int wid=threadIdx.x>>6;
  __syncthreads();
  if((threadIdx.x&63)==0) red4[wid]=v;
  __syncthreads();
  float4 s={0.f,0.f,0.f,0.f};
  #pragma unroll
  for(int k=0;k<8;k++){ float4 r=red4[k]; s.x+=r.x; s.y+=r.y; s.z+=r.z; s.w+=r.w; }
  return s;
}
__device__ __forceinline__ float4 blockMin512_v4(float4 v, float4* red4){
  #pragma unroll
  for(int o=32;o>0;o>>=1){
    v.x=fminf(v.x,__shfl_xor(v.x,o,64)); v.y=fminf(v.y,__shfl_xor(v.y,o,64));
    v.z=fminf(v.z,__shfl_xor(v.z,o,64)); v.w=fminf(v.w,__shfl_xor(v.w,o,64));
  }
  const int wid=threadIdx.x>>6;
  __syncthreads();
  if((threadIdx.x&63)==0) red4[wid]=v;
  __syncthreads();
  float4 s=red4[0];
  #pragma unroll
  for(int k=1;k<8;k++){ float4 r=red4[k]; s.x=fminf(s.x,r.x); s.y=fminf(s.y,r.y); s.z=fminf(s.z,r.z); s.w=fminf(s.w,r.w); }
  return s;
}

// K1: q/k/v projections, expmap0(q), expmap0(k), norms, v_r init, + transposed k_hypT
__global__ __launch_bounds__(64) void k_proj(
  const float* __restrict__ qin, const float* __restrict__ kin, const float* __restrict__ vin,
  const float* __restrict__ Wq, const float* __restrict__ bq,
  const float* __restrict__ Wk, const float* __restrict__ bk,
  const float* __restrict__ Wv, const float* __restrict__ bv,
  const float* __restrict__ vrand,
  float* __restrict__ q_hyp, float* __restrict__ k_hyp, float* __restrict__ kT,
  float* __restrict__ vproj, float* __restrict__ kproj,
  float* __restrict__ q2, float* __restrict__ k2, float* __restrict__ v_r)
{
  const int i = blockIdx.x, d = threadIdx.x;
  __shared__ __align__(16) float lq[D], lk[D], lv[D];
  lq[d]=qin[i*D+d]; lk[d]=kin[i*D+d]; lv[d]=vin[i*D+d];
  __syncthreads();
  float aq=bq[d], ak=bk[d], av=bv[d];
  const float4* wq4=(const float4*)(Wq + d*D);
  const float4* wk4=(const float4*)(Wk + d*D);
  const float4* wv4=(const float4*)(Wv + d*D);
  #pragma unroll
  for(int e=0;e<16;e++){
    float4 a=wq4[e], b=wk4[e], c=wv4[e];
    aq += lq[4*e]*a.x + lq[4*e+1]*a.y + lq[4*e+2]*a.z + lq[4*e+3]*a.w;
    ak += lk[4*e]*b.x + lk[4*e+1]*b.y + lk[4*e+2]*b.z + lk[4*e+3]*b.w;
    av += lv[4*e]*c.x + lv[4*e+1]*c.y + lv[4*e+2]*c.z + lv[4*e+3]*c.w;
  }
  float nq = sqrtf(waveSum(aq*aq)+1e-15f);
  float qh = tanhf(nq)*aq/nq;
  q_hyp[i*D+d]=qh;
  float q2v = waveSum(qh*qh);
  if(d==0) q2[i]=q2v;
  float nk = sqrtf(waveSum(ak*ak)+1e-15f);
  float kh = tanhf(nk)*ak/nk;
  k_hyp[i*D+d]=kh;
  kT[(size_t)d*S + i]=kh;
  float k2v = waveSum(kh*kh);
  if(d==0) k2[i]=k2v;
  vproj[i*D+d]=av;
  kproj[i*D+d]=ak;
  float vr = vrand[i*D+d];
  float nn = sqrtf(waveSum(vr*vr));
  v_r[i*D+d] = vr/fmaxf(nn,1e-12f);
}

// K2 (fused, register-resident K): 4 queries/block, 512 threads, grid 256.
// Thread (jf,dh) holds Y = k_hyp[j=4jf..4jf+3][d=32dh..32dh+31] in 32xfloat4 VGPRs.
// P1/PA/PB-pass1 are pure register FMA sweeps (q/c/v broadcast from LDS [d][4q]).
// PB-pass2 and P2 remain coalesced global sweeps.
__global__ __launch_bounds__(512,2) void k_fused(
  const float* __restrict__ q_hyp_g, const float* __restrict__ k_hyp,
  const float* __restrict__ kT,
  const float* __restrict__ q2a, const float* __restrict__ k2a,
  const float* __restrict__ vproj, const float* __restrict__ kproj,
  const float* __restrict__ v_r, const float* __restrict__ tau_p,
  const float* __restrict__ gu, const float* __restrict__ gamma_p,
  const float* __restrict__ ts_p, const float* __restrict__ Wo,
  const float* __restrict__ bo, float* __restrict__ out)
{
  const int i0=blockIdx.x*4, tid=threadIdx.x;
  __shared__ __align__(16) float qvT[D*4];     // [d][q]
  __shared__ __align__(16) float cvT[D*4];
  __shared__ __align__(16) float vvT[D*4];
  __shared__ __align__(16) float hl[4][D];
  __shared__ __align__(16) float fus[4][D];
  __shared__ __align__(16) float wl[4][S];     // w; aliased as prow in PB
  __shared__ __align__(16) float aal[4][S];
  __shared__ __align__(16) float bbl[4][S];
  __shared__ __align__(16) float4 sA[2048];    // 32KB pjoin / part buffer
  __shared__ __align__(16) float4 red4[8];
  __shared__ float scal[4][6];  // 0:var 1:tension 2:cdot 3:effm 4:c2
  float* const pA=(float*)sA;

  const int jf=tid&255, dh=tid>>8;
  const int qq0=dh, qq1=dh+2;
  const int dq=tid&15, g=tid>>4;
  const float tau=tau_p[0];
  const float4* kT4=(const float4*)kT;

  // ---- load Y into registers (one kT sweep, coalesced) ----
  float4 Y[32];
  #pragma unroll
  for(int dd=0;dd<32;dd++) Y[dd]=kT4[(dh*32+dd)*256+jf];

  if(tid<256){
    const int q=tid>>6, d=tid&63;
    qvT[d*4+q]=q_hyp_g[(i0+q)*D+d];
    vvT[d*4+q]=v_r[(i0+q)*D+d];
  }
  __syncthreads();

  // ================= P1: weights (register sweep) =================
  {
    float4 p0={0,0,0,0},p1={0,0,0,0},p2={0,0,0,0},p3={0,0,0,0};
    #pragma unroll
    for(int dd=0;dd<32;dd++){
      const float4 qd=*(const float4*)&qvT[(dh*32+dd)*4];
      FMA4(p0,qd.x,Y[dd]); FMA4(p1,qd.y,Y[dd]);
      FMA4(p2,qd.z,Y[dd]); FMA4(p3,qd.w,Y[dd]);
    }
    sA[(dh*4+0)*256+jf]=p0; sA[(dh*4+1)*256+jf]=p1;
    sA[(dh*4+2)*256+jf]=p2; sA[(dh*4+3)*256+jf]=p3;
  }
  __syncthreads();
  float4 inv4;
  {
    const float4 y2v=((const float4*)k2a)[jf];
    const float x2q[2]={q2a[i0+qq0], q2a[i0+qq1]};
    float dist[2][4];
    float4 mn4={FINF,FINF,FINF,FINF};
    #pragma unroll
    for(int it=0; it<2; ++it){
      const int qq = it? qq1:qq0;
      const float4 da=sA[(0*4+qq)*256+jf], db=sA[(1*4+qq)*256+jf];
      const float x2=x2q[it], B=1.f-x2;
      #pragma unroll
      for(int c=0;c<4;c++){
        const float y2=C4(y2v,c);
        const float dot=C4(da,c)+C4(db,c);
        const float A=1.f-2.f*dot+y2;
        const float den=fmaxf(1.f-2.f*dot+x2*y2,1e-15f);
        const float num2=fmaxf(A*A*x2 + B*B*y2 - 2.f*A*B*dot, 0.f);
        const float nn=sqrtf(num2/(den*den)+1e-15f);
        dist[it][c]=2.f*atanhf(fminf(nn,BND));
        C4(mn4,qq)=fminf(C4(mn4,qq),dist[it][c]);
      }
    }
    mn4=blockMin512_v4(mn4,red4);
    float w[2][4];
    float4 s4={0,0,0,0};
    #pragma unroll
    for(int it=0; it<2; ++it){
      const int qq = it? qq1:qq0;
      #pragma unroll
      for(int c=0;c<4;c++){ w[it][c]=expf(C4(mn4,qq)-dist[it][c]); C4(s4,qq)+=w[it][c]; }
      ((float4*)&wl[qq][0])[jf]=mk4(w[it]);
    }
    s4=blockSum512_v4(s4,red4);
    inv4.x=1.f/(s4.x+1e-8f); inv4.y=1.f/(s4.y+1e-8f);
    inv4.z=1.f/(s4.z+1e-8f); inv4.w=1.f/(s4.w+1e-8f);
    float4 e4={0,0,0,0};
    #pragma unroll
    for(int it=0; it<2; ++it){
      const int qq = it? qq1:qq0;
      #pragma unroll
      for(int c=0;c<4;c++){
        const float p=w[it][c]*C4(inv4,qq);
        C4(e4,qq) -= p*logf(p+1e-8f);
      }
    }
    e4=blockSum512_v4(e4,red4);
    if(tid<4) scal[tid][3]=expf(C4(e4,tid));
  }

  // ================= P2: h + centroid (global sweeps) =================
  {
    float4 a0={0,0,0,0},a1={0,0,0,0},a2={0,0,0,0},a3={0,0,0,0};
    #pragma unroll 4
    for(int jj=0;jj<32;jj++){
      const int j=jj*32+g;
      const float4 y=((const float4*)(vproj + j*D))[dq];
      const float u0=wl[0][j],u1=wl[1][j],u2=wl[2][j],u3=wl[3][j];
      FMA4(a0,u0,y); FMA4(a1,u1,y); FMA4(a2,u2,y); FMA4(a3,u3,y);
    }
    __syncthreads();   // P1 combine's sA reads done before overwrite
    *(float4*)&pA[(g*4+0)*64+dq*4]=a0; *(float4*)&pA[(g*4+1)*64+dq*4]=a1;
    *(float4*)&pA[(g*4+2)*64+dq*4]=a2; *(float4*)&pA[(g*4+3)*64+dq*4]=a3;
    __syncthreads();
    if(tid<256){
      const int q=tid>>6, d=tid&63;
      float hs=0.f;
      #pragma unroll 8
      for(int gg=0;gg<32;gg++) hs+=pA[(gg*4+q)*64+d];
      hl[q][d]=hs*C4(inv4,q);
    }
    __syncthreads();
    float4 b0={0,0,0,0},b1={0,0,0,0},b2={0,0,0,0},b3={0,0,0,0};
    #pragma unroll 4
    for(int jj=0;jj<32;jj++){
      const int j=jj*32+g;
      const float4 y=((const float4*)(kproj + j*D))[dq];
      const float u0=wl[0][j],u1=wl[1][j],u2=wl[2][j],u3=wl[3][j];
      FMA4(b0,u0,y); FMA4(b1,u1,y); FMA4(b2,u2,y); FMA4(b3,u3,y);
    }
    *(float4*)&pA[(g*4+0)*64+dq*4]=b0; *(float4*)&pA[(g*4+1)*64+dq*4]=b1;
    *(float4*)&pA[(g*4+2)*64+dq*4]=b2; *(float4*)&pA[(g*4+3)*64+dq*4]=b3;
    __syncthreads();
    if(tid<256){
      const int q=tid>>6, d=tid&63;
      float cs=0.f;
      #pragma unroll 8
      for(int gg=0;gg<32;gg++) cs+=pA[(gg*4+q)*64+d];
      const float ca=cs*C4(inv4,q);
      const float n=sqrtf(waveSum(ca*ca)+1e-15f);
      const float ch=tanhf(n)*ca/n;
      cvT[d*4+q]=ch;
      const float c2v=waveSum(ch*ch);
      // initial cdot for power iteration
      const float cd=waveSum(ch*vvT[d*4+q]);
      if(d==0){ scal[q][4]=c2v; scal[q][2]=cd; }
    }
  }
  __syncthreads();

  // ================= PA: coefficients (register sweep) =================
  {
    float4 p0={0,0,0,0},p1={0,0,0,0},p2={0,0,0,0},p3={0,0,0,0};
    #pragma unroll
    for(int dd=0;dd<32;dd++){
      const float4 cd4=*(const float4*)&cvT[(dh*32+dd)*4];
      FMA4(p0,cd4.x,Y[dd]); FMA4(p1,cd4.y,Y[dd]);
      FMA4(p2,cd4.z,Y[dd]); FMA4(p3,cd4.w,Y[dd]);
    }
    sA[(dh*4+0)*256+jf]=p0; sA[(dh*4+1)*256+jf]=p1;
    sA[(dh*4+2)*256+jf]=p2; sA[(dh*4+3)*256+jf]=p3;
  }
  __syncthreads();
  {
    const float4 y2v=((const float4*)k2a)[jf];
    float4 var4={0,0,0,0};
    #pragma unroll
    for(int it=0; it<2; ++it){
      const int qq = it? qq1:qq0;
      const float4 da=sA[(0*4+qq)*256+jf], db=sA[(1*4+qq)*256+jf];
      const float4 wv=((float4*)&wl[qq][0])[jf];
      const float x2=scal[qq][4];
      const float Bc=1.f-x2, mB=fmaxf(Bc,1e-15f), inv=C4(inv4,qq);
      float ac[4], bc[4];
      #pragma unroll
      for(int c=0;c<4;c++){
        const float y2=C4(y2v,c);
        const float dot=C4(da,c)+C4(db,c);
        const float A=1.f-2.f*dot+y2;
        const float den=fmaxf(1.f-2.f*dot+x2*y2,1e-15f);
        const float num2=fmaxf(A*A*x2+Bc*Bc*y2-2.f*A*Bc*dot,0.f);
        const float nn=sqrtf(num2/(den*den)+1e-15f);
        const float art=atanhf(fminf(nn,BND));
        const float w=C4(wv,c);
        C4(var4,qq) += w*inv*4.f*art*art;
        const float coef=sqrtf(w+1e-8f)*mB*art/(nn*den);
        ac[c]=-coef*A; bc[c]=coef*Bc;
      }
      ((float4*)&aal[qq][0])[jf]=mk4(ac);
      ((float4*)&bbl[qq][0])[jf]=mk4(bc);
    }
    var4=blockSum512_v4(var4,red4);
    if(tid<4){ scal[tid][0]=C4(var4,tid); scal[tid][1]=C4(var4,tid) - tau*scal[tid][3]; }
  }
  // wl dead; alias as prow[4][S]
  float* const prow0=&wl[0][0];

  // ================= PB: 3 power iterations =================
  for(int it3=0; it3<3; ++it3){
    __syncthreads();  // vvT/scal published; sA free
    // pass 1: register sweep with vvT
    {
      float4 p0={0,0,0,0},p1={0,0,0,0},p2={0,0,0,0},p3={0,0,0,0};
      #pragma unroll
      for(int dd=0;dd<32;dd++){
        const float4 vd4=*(const float4*)&vvT[(dh*32+dd)*4];
        FMA4(p0,vd4.x,Y[dd]); FMA4(p1,vd4.y,Y[dd]);
        FMA4(p2,vd4.z,Y[dd]); FMA4(p3,vd4.w,Y[dd]);
      }
      sA[(dh*4+0)*256+jf]=p0; sA[(dh*4+1)*256+jf]=p1;
      sA[(dh*4+2)*256+jf]=p2; sA[(dh*4+3)*256+jf]=p3;
    }
    __syncthreads();
    float4 sal4={0,0,0,0};
    {
      const float cdq[2]={scal[qq0][2], scal[qq1][2]};
      #pragma unroll
      for(int it=0; it<2; ++it){
        const int qq = it? qq1:qq0;
        const float4 da=sA[(0*4+qq)*256+jf], db=sA[(1*4+qq)*256+jf];
        const float4 av=((float4*)&aal[qq][0])[jf];
        const float4 bv=((float4*)&bbl[qq][0])[jf];
        float pr[4];
        #pragma unroll
        for(int c=0;c<4;c++){
          const float t=C4(da,c)+C4(db,c);
          const float p=C4(av,c)*cdq[it] + C4(bv,c)*t;
          pr[c]=p*C4(bv,c);
          C4(sal4,qq) += p*C4(av,c);
        }
        ((float4*)&prow0[qq*S])[jf]=mk4(pr);
      }
    }
    sal4=blockSum512_v4(sal4,red4);   // also publishes prow
    // pass 2: coalesced global k_hyp sweep
    {
      float4 a0={0,0,0,0},a1={0,0,0,0},a2={0,0,0,0},a3={0,0,0,0};
      #pragma unroll 4
      for(int jj=0;jj<32;jj++){
        const int j=jj*32+g;
        const float4 y=((const float4*)(k_hyp + j*D))[dq];
        const float u0=prow0[0*S+j],u1=prow0[1*S+j],u2=prow0[2*S+j],u3=prow0[3*S+j];
        FMA4(a0,u0,y); FMA4(a1,u1,y); FMA4(a2,u2,y); FMA4(a3,u3,y);
      }
      *(float4*)&pA[(g*4+0)*64+dq*4]=a0; *(float4*)&pA[(g*4+1)*64+dq*4]=a1;
      *(float4*)&pA[(g*4+2)*64+dq*4]=a2; *(float4*)&pA[(g*4+3)*64+dq*4]=a3;
    }
    __syncthreads();
    if(tid<256){
      const int q=tid>>6, d=tid&63;
      float od=C4(sal4,q)*cvT[d*4+q];
      #pragma unroll 8
      for(int gg=0;gg<32;gg++) od += pA[(gg*4+q)*64+d];
      const float nn=sqrtf(waveSum(od*od));
      const float vn=od/fmaxf(nn,1e-12f);
      vvT[d*4+q]=vn;
      const float cd=waveSum(cvT[d*4+q]*vn);   // cdot for next iteration
      if(d==0) scal[q][2]=cd;
    }
  }
  __syncthreads();

  // ================= PC: epilogue + out GEMV =================
  if(tid<256){
    const int q=tid>>6, d=tid&63;
    const int i=i0+q;
    const float x2q_c=scal[q][4];
    const float vd=vvT[d*4+q];
    const float vars=scal[q][0], tns=scal[q][1];
    const float hd=hl[q][d];
    const float qd=qvT[d*4+q];
    const float q2=q2a[i];
    const float wpg=vd/fmaxf(1.f-x2q_c,1e-15f);
    const float nq=sqrtf(q2+1e-15f);
    const float qt=atanhf(fminf(nq,BND))*qd/nq;
    const float ncn=sqrtf(x2q_c+1e-15f);
    const float ct=atanhf(fminf(ncn,BND))*cvT[d*4+q]/ncn;
    const float df=qt-ct;
    const float nd=sqrtf(waveSum(df*df));
    const float fb=df/fmaxf(nd,1e-8f);
    const float wp=(vars>1e-5f)?wpg:fb;
    const float hn=sqrtf(waveSum(hd*hd)+1e-15f);
    const float hc=asinhf(hn)*hd/(hn+1e-8f);
    const float x=waveSum(hc*wp);
    const float hmag=sqrtf(waveSum(hc*hc)+1e-15f);
    const float amp=(tns>0.f)? hmag*tanhf(tns) : 0.f;
    const float u0=gu[i*2], u1=gu[i*2+1];
    const float eg=(u0>=u1)?1.f:-1.f;
    const float dc=tanhf(eg*amp - x);
    const float hp=hc+dc*wp;
    const float hpn=sqrtf(waveSum(hp*hp)+1e-15f)+1e-8f;
    const float hpb=hp*(tanhf(hpn*ts_p[0])/hpn);
    const float n2=sqrtf(waveSum(hpb*hpb)+1e-15f);
    const float hyp=tanhf(n2)*hpb/n2;
    const float n3=sqrtf(waveSum(hyp*hyp)+1e-15f);
    const float bif=atanhf(fminf(n3,BND))*hyp/n3;
    const float gate=1.f/(1.f+expf(-gamma_p[0]));
    fus[q][d]=(1.f-gate)*hd + gate*bif;
  }
  __syncthreads();
  if(tid<256){
    const int q=tid>>6, d=tid&63;
    float acc=bo[d];
    const float4* wo4=(const float4*)(Wo + d*D);
    #pragma unroll
    for(int e=0;e<16;e++){
      float4 wv=wo4[e];
      acc += fus[q][4*e]*wv.x + fus[q][4*e+1]*wv.y + fus[q][4*e+2]*wv.z + fus[q][4*e+3]*wv.w;
    }
    out[(i0+q)*D+d]=acc;
  }
}

extern "C" void kernel_launch(void* const* d_in, const int* in_sizes, int n_in,
                              void* d_out, int out_size, void* d_ws, size_t ws_size,
                              hipStream_t stream)
{
  const float* qin=(const float*)d_in[0];
  const float* kin=(const float*)d_in[1];
  const float* vin=(const float*)d_in[2];
  const float* Wq=(const float*)d_in[3];
  const float* bq=(const float*)d_in[4];
  const float* Wk=(const float*)d_in[5];
  const float* bk=(const float*)d_in[6];
  const float* Wv=(const float*)d_in[7];
  const float* bv=(const float*)d_in[8];
  const float* Wo=(const float*)d_in[9];
  const float* bo=(const float*)d_in[10];
  const float* tau=(const float*)d_in[11];
  const float* gamma=(const float*)d_in[12];
  const float* tscale=(const float*)d_in[13];
  const float* gu=(const float*)d_in[14];
  const float* vrand=(const float*)d_in[15];
  float* out=(float*)d_out;

  float* p=(float*)d_ws;
  float* q_hyp=p; p+=S*D;
  float* k_hyp=p; p+=S*D;
  float* kT=p;    p+=S*D;
  float* vproj=p; p+=S*D;
  float* kproj=p; p+=S*D;
  float* v_r=p;   p+=S*D;
  float* q2=p;   p+=S;
  float* k2=p;   p+=S;

  k_proj<<<S,64,0,stream>>>(qin,kin,vin,Wq,bq,Wk,bk,Wv,bv,vrand,
                            q_hyp,k_hyp,kT,vproj,kproj,q2,k2,v_r);
  k_fused<<<S/4,512,0,stream>>>(q_hyp,k_hyp,kT,q2,k2,vproj,kproj,v_r,
                                tau,gu,gamma,tscale,Wo,bo,out);
}